// Round 2
// baseline (232.451 us; speedup 1.0000x reference)
//
#include <hip/hip_runtime.h>

// Biaffine: out[b,x,y] = Daug[b,x,:]·U·H[b,y,:] + Daug[b,x,:]·W[:d+1] + H[b,y,:]·W[d+1:]
// B=32, S=512, d=1024.  bf16 MFMA two-stage GEMM:
//   T = D @ U[0:d,:] + U[d,:]            (16384 x 1024 x 1024, bf16 out)
//   out[b] = T[b] @ H[b]^T + linD + linH (32 x 512x512x1024, fp32 out)
// R3: XOR-swizzled LDS layout (kept).
// R5: cast_rows restructured as pure stream + decoupled reduction.
//   R4 post-mortem: fusing load->shfl-reduce per row serialized on the 6-deep
//   DS shuffle chain (28 VGPR, VALUBusy 8%, 2.3 TB/s).  Now: block = 16 rows;
//   phase 1 = m13-style stream (thread t owns cols 4t..4t+3, 16 independent
//   float4 iters, block-invariant W chunk in regs, partials -> LDS);
//   phase 2 = one barrier + per-wave LDS reduce of 4 rows (tiny tail).

#define D_DIM 1024
#define ROWS 16384   // B*S

typedef float floatx4 __attribute__((ext_vector_type(4)));
typedef __bf16 bf16x8 __attribute__((ext_vector_type(8)));

__device__ inline unsigned short f2bf(float f) {
  unsigned int u = __builtin_bit_cast(unsigned int, f);
  u = (u + 0x7FFFu + ((u >> 16) & 1u)) >> 16;   // round-nearest-even
  return (unsigned short)u;
}

__device__ inline void async_load16(const void* g, void* l) {
  __builtin_amdgcn_global_load_lds(
      (const __attribute__((address_space(1))) void*)g,
      (__attribute__((address_space(3))) void*)l, 16, 0, 0);
}

// ---- cast D/H to bf16 + fused linear-term dot products ----------------------
// Block = 16 rows of one side.  1024 floats/row = 256 float4 = one iteration
// across 256 threads; thread t always owns columns 4t..4t+3 so its W chunk
// w4 is loaded once.  Phase 1: 16 independent {load,fma,cast,store,ds_write}
// iterations (pure stream).  Phase 2: wave w reduces rows 4w..4w+3 from LDS.
__global__ __launch_bounds__(256) void cast_rows_kernel(
    const float* __restrict__ D, const float* __restrict__ H,
    const float* __restrict__ W, const float* __restrict__ Wh,
    unsigned short* __restrict__ Dbf, unsigned short* __restrict__ Hbf,
    float* __restrict__ linD, float* __restrict__ linH) {
  __shared__ float lds[16][256];
  int t = threadIdx.x;
  bool isH = blockIdx.x >= 1024;
  int r0 = (blockIdx.x & 1023) * 16;
  const float* src = (isH ? H : D) + (size_t)r0 * D_DIM;
  unsigned short* dst = (isH ? Hbf : Dbf) + (size_t)r0 * D_DIM;
  float4 w4 = ((const float4*)(isH ? Wh : W))[t];   // both 16B-aligned

  #pragma unroll
  for (int i = 0; i < 16; ++i) {
    float4 v = ((const float4*)src)[i * 256 + t];
    lds[i][t] = v.x * w4.x + v.y * w4.y + v.z * w4.z + v.w * w4.w;
    ushort4 o;
    o.x = f2bf(v.x); o.y = f2bf(v.y); o.z = f2bf(v.z); o.w = f2bf(v.w);
    ((ushort4*)dst)[i * 256 + t] = o;
  }
  __syncthreads();

  int wave = t >> 6, l = t & 63;
  float* lin = isH ? linH : linD;
  float bias = isH ? 0.f : W[D_DIM];                // ones-column bias (D side)
  #pragma unroll
  for (int c = 0; c < 4; ++c) {                    // 4 independent chains
    int r = wave * 4 + c;
    float4 p = *(const float4*)&lds[r][4 * l];
    float s = p.x + p.y + p.z + p.w;
    #pragma unroll
    for (int off = 32; off > 0; off >>= 1) s += __shfl_down(s, off, 64);
    if (l == 0) lin[r0 + r] = s + bias;
  }
}

// ---- transpose U (first 1024 rows) to bf16 Ut[n][k] = U[k][n] ---------------
// Block (0,0) additionally stages Wh = W[d+1 : 2d+1] (aligned copy for the
// cast kernel's vectorized W loads).  transU is launched BEFORE cast_rows on
// the same stream, so Wh is ready.
__global__ __launch_bounds__(256) void transU_kernel(
    const float* __restrict__ U, const float* __restrict__ W,
    unsigned short* __restrict__ Ut, float* __restrict__ Wh) {
  if (blockIdx.x == 0 && blockIdx.y == 0) {
    #pragma unroll
    for (int i = 0; i < 4; ++i)
      Wh[threadIdx.x + 256 * i] = W[D_DIM + 1 + threadIdx.x + 256 * i];
  }
  __shared__ float tile[32][33];
  int n0 = blockIdx.x * 32;
  int k0 = blockIdx.y * 32;
  int t = threadIdx.x;
  int tr = t >> 5, tc = t & 31;
  #pragma unroll
  for (int i = 0; i < 32; i += 8)
    tile[tr + i][tc] = U[(size_t)(k0 + tr + i) * D_DIM + n0 + tc];
  __syncthreads();
  #pragma unroll
  for (int i = 0; i < 32; i += 8)
    Ut[(size_t)(n0 + tr + i) * D_DIM + k0 + tc] = f2bf(tile[tc][tr + i]);
}

// ---- swizzled MFMA K-loop core: 128x128 tile, BK=64 -------------------------
// LDS chunk (16B) for (row,q): c = (row>>3)*64 + (row&7)*8 + (q ^ (row&7)).
// Staging instr j (wave w): group g=j*4+w, lane l -> row 8g+(l>>3),
// q=(l&7)^(l>>3): 8 contiguous 128B global lines, LDS dest = base + lane*16.
// Frag read (row=W*64+mt*16+lrow, q=s*4+quad): 8-round minimum, no conflicts.
__device__ inline void gemm_core_swz(
    const unsigned short* __restrict__ A, const unsigned short* __restrict__ Bt,
    int m0, int n0, unsigned short* As, unsigned short* Bs,
    floatx4 (&acc)[4][4]) {
  const int K = D_DIM;
  int tid = threadIdx.x;
  int l = tid & 63, wave = tid >> 6;
  int quad = l >> 4, lrow = l & 15;
  int wm = wave >> 1, wn = wave & 1;

  int srow = 8 * wave + (l >> 3);              // +32*j per issue
  int sq = (l & 7) ^ (l >> 3);
  const unsigned short* gA = A + (size_t)(m0 + srow) * K + sq * 8;
  const unsigned short* gB = Bt + (size_t)(n0 + srow) * K + sq * 8;

  int rl = lrow & 7, gofs = lrow >> 3;
  int baseA = wm * 512 + gofs * 64 + rl * 8;
  int baseB = wn * 512 + gofs * 64 + rl * 8;

  for (int k0 = 0; k0 < K; k0 += 64) {
    __syncthreads();
    #pragma unroll
    for (int j = 0; j < 4; ++j) {
      async_load16(gA + (size_t)(32 * j) * K + k0, As + (j * 256 + tid) * 8);
      async_load16(gB + (size_t)(32 * j) * K + k0, Bs + (j * 256 + tid) * 8);
    }
    __syncthreads();
    #pragma unroll
    for (int s = 0; s < 2; ++s) {
      int xq = (s * 4 + quad) ^ rl;
      bf16x8 a[4], b[4];
      #pragma unroll
      for (int mt = 0; mt < 4; ++mt)
        a[mt] = *(const bf16x8*)(As + (baseA + mt * 128 + xq) * 8);
      #pragma unroll
      for (int nt = 0; nt < 4; ++nt)
        b[nt] = *(const bf16x8*)(Bs + (baseB + nt * 128 + xq) * 8);
      #pragma unroll
      for (int mt = 0; mt < 4; ++mt)
        #pragma unroll
        for (int nt = 0; nt < 4; ++nt)
          acc[mt][nt] = __builtin_amdgcn_mfma_f32_16x16x32_bf16(
              a[mt], b[nt], acc[mt][nt], 0, 0, 0);
    }
  }
}

// ---- GEMM1: T[m][n] = sum_k Dbf[m][k] * Ut[n][k] + Ubias[n], bf16 out -------
// grid (128, 8): id%8 = mtile%8 -> the 8 n-blocks sharing an A row-tile land
// on one XCD (A row-tile fetched once into that XCD's L2).
__global__ __launch_bounds__(256) void gemm1_kernel(
    const unsigned short* __restrict__ A,    // [16384,1024] bf16 bits
    const unsigned short* __restrict__ Bt,   // [1024,1024]  bf16 bits
    const float* __restrict__ Ubias,         // fp32, len 1024
    unsigned short* __restrict__ T) {
  __shared__ __align__(16) unsigned short As[128 * 64];
  __shared__ __align__(16) unsigned short Bs[128 * 64];
  int m0 = blockIdx.x * 128, n0 = blockIdx.y * 128;
  int tid = threadIdx.x;
  int lane = tid & 63, wave = tid >> 6;
  int quad = lane >> 4, lrow = lane & 15;
  int wm = wave >> 1, wn = wave & 1;

  floatx4 acc[4][4] = {};
  gemm_core_swz(A, Bt, m0, n0, As, Bs, acc);

  // C/D layout: col = lane&15, row = quad*4 + reg  [m89-verified]
  #pragma unroll
  for (int mt = 0; mt < 4; ++mt)
    #pragma unroll
    for (int nt = 0; nt < 4; ++nt) {
      int row = m0 + wm * 64 + mt * 16 + quad * 4;
      int col = n0 + wn * 64 + nt * 16 + lrow;
      float bias = Ubias[col];
      #pragma unroll
      for (int rr = 0; rr < 4; ++rr)
        T[(size_t)(row + rr) * D_DIM + col] = f2bf(acc[mt][nt][rr] + bias);
    }
}

// ---- GEMM2: out[b,x,y] = sum_k T[b,x,k]*Hbf[b,y,k] + linD[b,x] + linH[b,y] --
// grid (32, 16): id%8 = b%8 -> each batch's 16 blocks on one XCD;
// T[b]+H[b] = 4 MB ~ per-XCD L2.
__global__ __launch_bounds__(256) void gemm2_kernel(
    const unsigned short* __restrict__ Tg,   // [32*512,1024]
    const unsigned short* __restrict__ Hbf,  // [32*512,1024]
    const float* __restrict__ linD, const float* __restrict__ linH,
    float* __restrict__ out) {               // [32,512,512]
  __shared__ __align__(16) unsigned short As[128 * 64];
  __shared__ __align__(16) unsigned short Bs[128 * 64];
  int b = blockIdx.x;
  int t = blockIdx.y;
  int m0 = (t >> 2) * 128, n0 = (t & 3) * 128;
  const unsigned short* A = Tg + (size_t)b * 512 * D_DIM;
  const unsigned short* Bt = Hbf + (size_t)b * 512 * D_DIM;
  int tid = threadIdx.x;
  int lane = tid & 63, wave = tid >> 6;
  int quad = lane >> 4, lrow = lane & 15;
  int wm = wave >> 1, wn = wave & 1;

  floatx4 acc[4][4] = {};
  gemm_core_swz(A, Bt, m0, n0, As, Bs, acc);

  #pragma unroll
  for (int mt = 0; mt < 4; ++mt)
    #pragma unroll
    for (int nt = 0; nt < 4; ++nt) {
      int row = m0 + wm * 64 + mt * 16 + quad * 4;
      int col = n0 + wn * 64 + nt * 16 + lrow;
      float lh = linH[b * 512 + col];
      #pragma unroll
      for (int rr = 0; rr < 4; ++rr) {
        float v = acc[mt][nt][rr] + linD[b * 512 + row + rr] + lh;
        out[((size_t)b * 512 + row + rr) * 512 + col] = v;
      }
    }
}

extern "C" void kernel_launch(void* const* d_in, const int* in_sizes, int n_in,
                              void* d_out, int out_size, void* d_ws, size_t ws_size,
                              hipStream_t stream) {
  const float* D = (const float*)d_in[0];
  const float* H = (const float*)d_in[1];
  const float* U = (const float*)d_in[2];   // [1025,1024]
  const float* W = (const float*)d_in[3];   // [2049]
  float* out = (float*)d_out;

  char* ws = (char*)d_ws;
  unsigned short* Dbf = (unsigned short*)ws; ws += (size_t)ROWS * D_DIM * 2;   // 32 MB
  unsigned short* Hbf = (unsigned short*)ws; ws += (size_t)ROWS * D_DIM * 2;   // 32 MB
  unsigned short* Tbf = (unsigned short*)ws; ws += (size_t)ROWS * D_DIM * 2;   // 32 MB
  unsigned short* Ut  = (unsigned short*)ws; ws += (size_t)D_DIM * D_DIM * 2;  //  2 MB
  float* linD = (float*)ws;                  ws += (size_t)ROWS * 4;
  float* linH = (float*)ws;                  ws += (size_t)ROWS * 4;
  float* Wh   = (float*)ws;                  ws += (size_t)D_DIM * 4;          // aligned W[d+1:]

  // transU first: it stages Wh, which cast_rows consumes (same stream).
  transU_kernel<<<dim3(32, 32), 256, 0, stream>>>(U, W, Ut, Wh);
  cast_rows_kernel<<<dim3(2048), 256, 0, stream>>>(D, H, W, Wh, Dbf, Hbf, linD, linH);
  gemm1_kernel<<<dim3(128, 8), 256, 0, stream>>>(Dbf, Ut, U + (size_t)D_DIM * D_DIM, Tbf);
  gemm2_kernel<<<dim3(32, 16), 256, 0, stream>>>(Tbf, Hbf, linD, linH, out);
}

// Round 3
// 231.537 us; speedup vs baseline: 1.0039x; 1.0039x over previous
//
#include <hip/hip_runtime.h>

// Biaffine: out[b,x,y] = Daug[b,x,:]·U·H[b,y,:] + Daug[b,x,:]·W[:d+1] + H[b,y,:]·W[d+1:]
// B=32, S=512, d=1024.  bf16 MFMA two-stage GEMM:
//   T = D @ U[0:d,:] + U[d,:]            (16384 x 1024 x 1024, bf16 out)
//   out[b] = T[b] @ H[b]^T + linD + linH (32 x 512x512x1024, fp32 out)
// R3: XOR-swizzled LDS layout (kept).
// R6: cast_rows — kill the pointer-select aliasing hazard.
//   R5 post-mortem: VGPR=24 proved the compiler kept ~1 load in flight; the
//   `isH ? H : D` selects strip noalias, so loads can't hoist past the bf16
//   stores.  Now: branch-duplicated load bodies on the raw __restrict__
//   params, explicit v[16] register staging, sched_barrier(0) pinning all 16
//   loads before any use.  Expect VGPR ~90 and ~16x MLP per wave.

#define D_DIM 1024
#define ROWS 16384   // B*S

typedef float floatx4 __attribute__((ext_vector_type(4)));
typedef __bf16 bf16x8 __attribute__((ext_vector_type(8)));

__device__ inline unsigned short f2bf(float f) {
  unsigned int u = __builtin_bit_cast(unsigned int, f);
  u = (u + 0x7FFFu + ((u >> 16) & 1u)) >> 16;   // round-nearest-even
  return (unsigned short)u;
}

__device__ inline void async_load16(const void* g, void* l) {
  __builtin_amdgcn_global_load_lds(
      (const __attribute__((address_space(1))) void*)g,
      (__attribute__((address_space(3))) void*)l, 16, 0, 0);
}

// ---- cast D/H to bf16 + fused linear-term dot products ----------------------
// Block = 16 rows of one side.  Thread t owns cols 4t..4t+3 (W chunk in regs).
// Phase 1a: 16 float4 loads -> v[16] registers (direct on restrict param, no
// select) ; sched_barrier pins them above phase 1b.
// Phase 1b: fma partials -> LDS, cast -> bf16 store (pure stream-out).
// Phase 2: one barrier, wave w reduces rows 4w..4w+3 from LDS.
__global__ __launch_bounds__(256) void cast_rows_kernel(
    const float* __restrict__ D, const float* __restrict__ H,
    const float* __restrict__ W, const float* __restrict__ Wh,
    unsigned short* __restrict__ Dbf, unsigned short* __restrict__ Hbf,
    float* __restrict__ linD, float* __restrict__ linH) {
  __shared__ float lds[16][256];
  int t = threadIdx.x;
  bool isH = blockIdx.x >= 1024;
  int r0 = (blockIdx.x & 1023) * 16;
  size_t base = (size_t)r0 * D_DIM;

  float4 v[16];
  float4 w4;
  if (isH) {
    w4 = ((const float4*)Wh)[t];
    #pragma unroll
    for (int i = 0; i < 16; ++i)
      v[i] = ((const float4*)(H + base))[i * 256 + t];
  } else {
    w4 = ((const float4*)W)[t];
    #pragma unroll
    for (int i = 0; i < 16; ++i)
      v[i] = ((const float4*)(D + base))[i * 256 + t];
  }
  __builtin_amdgcn_sched_barrier(0);   // all 16 loads issued before any use

  if (isH) {
    #pragma unroll
    for (int i = 0; i < 16; ++i) {
      lds[i][t] = v[i].x * w4.x + v[i].y * w4.y + v[i].z * w4.z + v[i].w * w4.w;
      ushort4 o;
      o.x = f2bf(v[i].x); o.y = f2bf(v[i].y); o.z = f2bf(v[i].z); o.w = f2bf(v[i].w);
      ((ushort4*)(Hbf + base))[i * 256 + t] = o;
    }
  } else {
    #pragma unroll
    for (int i = 0; i < 16; ++i) {
      lds[i][t] = v[i].x * w4.x + v[i].y * w4.y + v[i].z * w4.z + v[i].w * w4.w;
      ushort4 o;
      o.x = f2bf(v[i].x); o.y = f2bf(v[i].y); o.z = f2bf(v[i].z); o.w = f2bf(v[i].w);
      ((ushort4*)(Dbf + base))[i * 256 + t] = o;
    }
  }
  __syncthreads();

  int wave = t >> 6, l = t & 63;
  float* lin = isH ? linH : linD;
  float bias = isH ? 0.f : W[D_DIM];                // ones-column bias (D side)
  #pragma unroll
  for (int c = 0; c < 4; ++c) {                    // 4 independent chains
    int r = wave * 4 + c;
    float4 p = *(const float4*)&lds[r][4 * l];
    float s = p.x + p.y + p.z + p.w;
    #pragma unroll
    for (int off = 32; off > 0; off >>= 1) s += __shfl_down(s, off, 64);
    if (l == 0) lin[r0 + r] = s + bias;
  }
}

// ---- transpose U (first 1024 rows) to bf16 Ut[n][k] = U[k][n] ---------------
// Block (0,0) additionally stages Wh = W[d+1 : 2d+1] (aligned copy for the
// cast kernel's vectorized W loads).  transU is launched BEFORE cast_rows on
// the same stream, so Wh is ready.
__global__ __launch_bounds__(256) void transU_kernel(
    const float* __restrict__ U, const float* __restrict__ W,
    unsigned short* __restrict__ Ut, float* __restrict__ Wh) {
  if (blockIdx.x == 0 && blockIdx.y == 0) {
    #pragma unroll
    for (int i = 0; i < 4; ++i)
      Wh[threadIdx.x + 256 * i] = W[D_DIM + 1 + threadIdx.x + 256 * i];
  }
  __shared__ float tile[32][33];
  int n0 = blockIdx.x * 32;
  int k0 = blockIdx.y * 32;
  int t = threadIdx.x;
  int tr = t >> 5, tc = t & 31;
  #pragma unroll
  for (int i = 0; i < 32; i += 8)
    tile[tr + i][tc] = U[(size_t)(k0 + tr + i) * D_DIM + n0 + tc];
  __syncthreads();
  #pragma unroll
  for (int i = 0; i < 32; i += 8)
    Ut[(size_t)(n0 + tr + i) * D_DIM + k0 + tc] = f2bf(tile[tc][tr + i]);
}

// ---- swizzled MFMA K-loop core: 128x128 tile, BK=64 -------------------------
// LDS chunk (16B) for (row,q): c = (row>>3)*64 + (row&7)*8 + (q ^ (row&7)).
// Staging instr j (wave w): group g=j*4+w, lane l -> row 8g+(l>>3),
// q=(l&7)^(l>>3): 8 contiguous 128B global lines, LDS dest = base + lane*16.
// Frag read (row=W*64+mt*16+lrow, q=s*4+quad): 8-round minimum, no conflicts.
__device__ inline void gemm_core_swz(
    const unsigned short* __restrict__ A, const unsigned short* __restrict__ Bt,
    int m0, int n0, unsigned short* As, unsigned short* Bs,
    floatx4 (&acc)[4][4]) {
  const int K = D_DIM;
  int tid = threadIdx.x;
  int l = tid & 63, wave = tid >> 6;
  int quad = l >> 4, lrow = l & 15;
  int wm = wave >> 1, wn = wave & 1;

  int srow = 8 * wave + (l >> 3);              // +32*j per issue
  int sq = (l & 7) ^ (l >> 3);
  const unsigned short* gA = A + (size_t)(m0 + srow) * K + sq * 8;
  const unsigned short* gB = Bt + (size_t)(n0 + srow) * K + sq * 8;

  int rl = lrow & 7, gofs = lrow >> 3;
  int baseA = wm * 512 + gofs * 64 + rl * 8;
  int baseB = wn * 512 + gofs * 64 + rl * 8;

  for (int k0 = 0; k0 < K; k0 += 64) {
    __syncthreads();
    #pragma unroll
    for (int j = 0; j < 4; ++j) {
      async_load16(gA + (size_t)(32 * j) * K + k0, As + (j * 256 + tid) * 8);
      async_load16(gB + (size_t)(32 * j) * K + k0, Bs + (j * 256 + tid) * 8);
    }
    __syncthreads();
    #pragma unroll
    for (int s = 0; s < 2; ++s) {
      int xq = (s * 4 + quad) ^ rl;
      bf16x8 a[4], b[4];
      #pragma unroll
      for (int mt = 0; mt < 4; ++mt)
        a[mt] = *(const bf16x8*)(As + (baseA + mt * 128 + xq) * 8);
      #pragma unroll
      for (int nt = 0; nt < 4; ++nt)
        b[nt] = *(const bf16x8*)(Bs + (baseB + nt * 128 + xq) * 8);
      #pragma unroll
      for (int mt = 0; mt < 4; ++mt)
        #pragma unroll
        for (int nt = 0; nt < 4; ++nt)
          acc[mt][nt] = __builtin_amdgcn_mfma_f32_16x16x32_bf16(
              a[mt], b[nt], acc[mt][nt], 0, 0, 0);
    }
  }
}

// ---- GEMM1: T[m][n] = sum_k Dbf[m][k] * Ut[n][k] + Ubias[n], bf16 out -------
// grid (128, 8): id%8 = mtile%8 -> the 8 n-blocks sharing an A row-tile land
// on one XCD (A row-tile fetched once into that XCD's L2).
__global__ __launch_bounds__(256) void gemm1_kernel(
    const unsigned short* __restrict__ A,    // [16384,1024] bf16 bits
    const unsigned short* __restrict__ Bt,   // [1024,1024]  bf16 bits
    const float* __restrict__ Ubias,         // fp32, len 1024
    unsigned short* __restrict__ T) {
  __shared__ __align__(16) unsigned short As[128 * 64];
  __shared__ __align__(16) unsigned short Bs[128 * 64];
  int m0 = blockIdx.x * 128, n0 = blockIdx.y * 128;
  int tid = threadIdx.x;
  int lane = tid & 63, wave = tid >> 6;
  int quad = lane >> 4, lrow = lane & 15;
  int wm = wave >> 1, wn = wave & 1;

  floatx4 acc[4][4] = {};
  gemm_core_swz(A, Bt, m0, n0, As, Bs, acc);

  // C/D layout: col = lane&15, row = quad*4 + reg  [m89-verified]
  #pragma unroll
  for (int mt = 0; mt < 4; ++mt)
    #pragma unroll
    for (int nt = 0; nt < 4; ++nt) {
      int row = m0 + wm * 64 + mt * 16 + quad * 4;
      int col = n0 + wn * 64 + nt * 16 + lrow;
      float bias = Ubias[col];
      #pragma unroll
      for (int rr = 0; rr < 4; ++rr)
        T[(size_t)(row + rr) * D_DIM + col] = f2bf(acc[mt][nt][rr] + bias);
    }
}

// ---- GEMM2: out[b,x,y] = sum_k T[b,x,k]*Hbf[b,y,k] + linD[b,x] + linH[b,y] --
// grid (32, 16): id%8 = b%8 -> each batch's 16 blocks on one XCD;
// T[b]+H[b] = 4 MB ~ per-XCD L2.
__global__ __launch_bounds__(256) void gemm2_kernel(
    const unsigned short* __restrict__ Tg,   // [32*512,1024]
    const unsigned short* __restrict__ Hbf,  // [32*512,1024]
    const float* __restrict__ linD, const float* __restrict__ linH,
    float* __restrict__ out) {               // [32,512,512]
  __shared__ __align__(16) unsigned short As[128 * 64];
  __shared__ __align__(16) unsigned short Bs[128 * 64];
  int b = blockIdx.x;
  int t = blockIdx.y;
  int m0 = (t >> 2) * 128, n0 = (t & 3) * 128;
  const unsigned short* A = Tg + (size_t)b * 512 * D_DIM;
  const unsigned short* Bt = Hbf + (size_t)b * 512 * D_DIM;
  int tid = threadIdx.x;
  int lane = tid & 63, wave = tid >> 6;
  int quad = lane >> 4, lrow = lane & 15;
  int wm = wave >> 1, wn = wave & 1;

  floatx4 acc[4][4] = {};
  gemm_core_swz(A, Bt, m0, n0, As, Bs, acc);

  #pragma unroll
  for (int mt = 0; mt < 4; ++mt)
    #pragma unroll
    for (int nt = 0; nt < 4; ++nt) {
      int row = m0 + wm * 64 + mt * 16 + quad * 4;
      int col = n0 + wn * 64 + nt * 16 + lrow;
      float lh = linH[b * 512 + col];
      #pragma unroll
      for (int rr = 0; rr < 4; ++rr) {
        float v = acc[mt][nt][rr] + linD[b * 512 + row + rr] + lh;
        out[((size_t)b * 512 + row + rr) * 512 + col] = v;
      }
    }
}

extern "C" void kernel_launch(void* const* d_in, const int* in_sizes, int n_in,
                              void* d_out, int out_size, void* d_ws, size_t ws_size,
                              hipStream_t stream) {
  const float* D = (const float*)d_in[0];
  const float* H = (const float*)d_in[1];
  const float* U = (const float*)d_in[2];   // [1025,1024]
  const float* W = (const float*)d_in[3];   // [2049]
  float* out = (float*)d_out;

  char* ws = (char*)d_ws;
  unsigned short* Dbf = (unsigned short*)ws; ws += (size_t)ROWS * D_DIM * 2;   // 32 MB
  unsigned short* Hbf = (unsigned short*)ws; ws += (size_t)ROWS * D_DIM * 2;   // 32 MB
  unsigned short* Tbf = (unsigned short*)ws; ws += (size_t)ROWS * D_DIM * 2;   // 32 MB
  unsigned short* Ut  = (unsigned short*)ws; ws += (size_t)D_DIM * D_DIM * 2;  //  2 MB
  float* linD = (float*)ws;                  ws += (size_t)ROWS * 4;
  float* linH = (float*)ws;                  ws += (size_t)ROWS * 4;
  float* Wh   = (float*)ws;                  ws += (size_t)D_DIM * 4;          // aligned W[d+1:]

  // transU first: it stages Wh, which cast_rows consumes (same stream).
  transU_kernel<<<dim3(32, 32), 256, 0, stream>>>(U, W, Ut, Wh);
  cast_rows_kernel<<<dim3(2048), 256, 0, stream>>>(D, H, W, Wh, Dbf, Hbf, linD, linH);
  gemm1_kernel<<<dim3(128, 8), 256, 0, stream>>>(Dbf, Ut, U + (size_t)D_DIM * D_DIM, Tbf);
  gemm2_kernel<<<dim3(32, 16), 256, 0, stream>>>(Tbf, Hbf, linD, linH, out);
}

// Round 4
// 226.257 us; speedup vs baseline: 1.0274x; 1.0233x over previous
//
#include <hip/hip_runtime.h>

// Biaffine: out[b,x,y] = Daug[b,x,:]·U·H[b,y,:] + Daug[b,x,:]·W[:d+1] + H[b,y,:]·W[d+1:]
// B=32, S=512, d=1024.  bf16 MFMA two-stage GEMM, CASTS FUSED INTO THE GEMMS:
//   gemm1: T = bf16(D) @ Ut^T + U[d,:]   (A = fp32 D, reg-staged cast -> LDS;
//          y==0 blocks also compute linD = Daug·W[:d+1] during staging)
//   gemm2: out[b] = T[b] @ bf16(H[b])^T + linD + linH
//          (B = fp32 H, reg-staged cast; each block computes its cols' linH
//           in-LDS, never written to global)
// R7: cast_rows_kernel DELETED.  R4-R6 post-mortem: the standalone cast pass
//   was pinned at 2.2-2.6 TB/s (latency/LLC-thrash-bound) across three
//   structurally different rewrites; cheapest fix is to not run the pass.
//   Reg-staging works here (vs R6's failure) because the staging stores are
//   LDS address-space -> no alias hazard with the global loads.
// R3 swizzle kept: LDS chunk (16B) for (row,q): c=(row>>3)*64+(row&7)*8+(q^(row&7)).

#define D_DIM 1024
#define ROWS 16384   // B*S

typedef float floatx4 __attribute__((ext_vector_type(4)));
typedef __bf16 bf16x8 __attribute__((ext_vector_type(8)));
typedef __bf16 bf16x4 __attribute__((ext_vector_type(4)));

__device__ inline unsigned short f2bf(float f) {
  unsigned int u = __builtin_bit_cast(unsigned int, f);
  u = (u + 0x7FFFu + ((u >> 16) & 1u)) >> 16;   // round-nearest-even
  return (unsigned short)u;
}

__device__ inline void async_load16(const void* g, void* l) {
  __builtin_amdgcn_global_load_lds(
      (const __attribute__((address_space(1))) void*)g,
      (__attribute__((address_space(3))) void*)l, 16, 0, 0);
}

// ---- transpose U (first 1024 rows) to bf16 Ut[n][k] = U[k][n] ---------------
// Block (0,0) additionally stages Wh = W[d+1 : 2d+1] (aligned copy; the raw
// offset is 4B-misaligned).  transU runs first on the stream.
__global__ __launch_bounds__(256) void transU_kernel(
    const float* __restrict__ U, const float* __restrict__ W,
    unsigned short* __restrict__ Ut, float* __restrict__ Wh) {
  if (blockIdx.x == 0 && blockIdx.y == 0) {
    #pragma unroll
    for (int i = 0; i < 4; ++i)
      Wh[threadIdx.x + 256 * i] = W[D_DIM + 1 + threadIdx.x + 256 * i];
  }
  __shared__ float tile[32][33];
  int n0 = blockIdx.x * 32;
  int k0 = blockIdx.y * 32;
  int t = threadIdx.x;
  int tr = t >> 5, tc = t & 31;
  #pragma unroll
  for (int i = 0; i < 32; i += 8)
    tile[tr + i][tc] = U[(size_t)(k0 + tr + i) * D_DIM + n0 + tc];
  __syncthreads();
  #pragma unroll
  for (int i = 0; i < 32; i += 8)
    Ut[(size_t)(n0 + tr + i) * D_DIM + k0 + tc] = f2bf(tile[tc][tr + i]);
}

// ---- mixed-operand MFMA core: 128x128 tile, BK=64 ---------------------------
// One operand (bf16, row-major [row][k]) staged via global_load_lds with the
// pre-swizzled-source trick; the other operand arrives as fp32 and is
// reg-staged: coalesced float4 loads (thread t covers quad qi=t&15 of rows
// 16i+(t>>4)), cvt_pk -> bf16, ds_write_b64 at the swizzled address.
// While staging fp32, optionally accumulate per-row dot partials vs Wv
// (part[i] belongs to row 16i+(t>>4); 16 threads share a row -> LDS-reduce
// later in the caller).
template <bool F32_IS_A>
__device__ inline void gemm_core_mixed(
    const unsigned short* __restrict__ Ga,  // async bf16 side, tile row 0
    const float* __restrict__ Gf,           // fp32 side, tile row 0
    const float* __restrict__ Wv,           // lin weights (len >= 1024)
    bool do_lin, float (&part)[8],
    unsigned short* As, unsigned short* Bs,
    floatx4 (&acc)[4][4]) {
  const int K = D_DIM;
  int tid = threadIdx.x;
  int l = tid & 63, wave = tid >> 6;
  int quad = l >> 4, lrow = l & 15;
  int wm = wave >> 1, wn = wave & 1;

  unsigned short* Sasync = F32_IS_A ? Bs : As;
  unsigned short* Sf32   = F32_IS_A ? As : Bs;

  int srow = 8 * wave + (l >> 3);              // +32*j per issue
  int sq = (l & 7) ^ (l >> 3);
  const unsigned short* gasync = Ga + (size_t)srow * K + sq * 8;

  int rl = lrow & 7, gofs = lrow >> 3;
  int baseA = wm * 512 + gofs * 64 + rl * 8;
  int baseB = wn * 512 + gofs * 64 + rl * 8;

  int qi = tid & 15;                           // fp32 side: quad index in BK
  const float* gf = Gf + (size_t)(tid >> 4) * K + qi * 4;

  for (int k0 = 0; k0 < K; k0 += 64) {
    __syncthreads();
    #pragma unroll
    for (int j = 0; j < 4; ++j)
      async_load16(gasync + (size_t)(32 * j) * K + k0, Sasync + (j * 256 + tid) * 8);
    // fp32 side: 8 rows (16 apart), fully coalesced (16 lanes = one row's 256B)
    float4 v[8];
    #pragma unroll
    for (int i = 0; i < 8; ++i)
      v[i] = *(const float4*)(gf + (size_t)(16 * i) * K + k0);
    float4 wq;
    if (do_lin) wq = *(const float4*)(Wv + k0 + qi * 4);
    #pragma unroll
    for (int i = 0; i < 8; ++i) {
      if (do_lin)
        part[i] += v[i].x * wq.x + v[i].y * wq.y + v[i].z * wq.z + v[i].w * wq.w;
      int row = 16 * i + (tid >> 4);
      int q = qi >> 1, half = qi & 1;
      int c = (row >> 3) * 64 + (row & 7) * 8 + (q ^ (row & 7));
      bf16x4 o = { (__bf16)v[i].x, (__bf16)v[i].y, (__bf16)v[i].z, (__bf16)v[i].w };
      *(bf16x4*)(Sf32 + c * 8 + half * 4) = o;   // ds_write_b64, conflict-free
    }
    __syncthreads();
    #pragma unroll
    for (int s = 0; s < 2; ++s) {
      int xq = (s * 4 + quad) ^ rl;
      bf16x8 a[4], b[4];
      #pragma unroll
      for (int mt = 0; mt < 4; ++mt)
        a[mt] = *(const bf16x8*)(As + (baseA + mt * 128 + xq) * 8);
      #pragma unroll
      for (int nt = 0; nt < 4; ++nt)
        b[nt] = *(const bf16x8*)(Bs + (baseB + nt * 128 + xq) * 8);
      #pragma unroll
      for (int mt = 0; mt < 4; ++mt)
        #pragma unroll
        for (int nt = 0; nt < 4; ++nt)
          acc[mt][nt] = __builtin_amdgcn_mfma_f32_16x16x32_bf16(
              a[mt], b[nt], acc[mt][nt], 0, 0, 0);
    }
  }
}

// ---- GEMM1: T[m][n] = sum_k bf16(D[m][k]) * Ut[n][k] + Ubias[n], bf16 out ---
// A = fp32 D (reg-staged cast); B = Ut (async).  y==0 blocks compute linD.
// grid (128, 8): id%8 = mtile%8 -> 8 n-blocks sharing an A row-tile per XCD.
__global__ __launch_bounds__(256) void gemm1_kernel(
    const float* __restrict__ Df,            // [16384,1024] fp32
    const unsigned short* __restrict__ Ut,   // [1024,1024]  bf16 bits
    const float* __restrict__ Ubias,         // fp32, len 1024 (row d of U)
    const float* __restrict__ W,             // [2049] fp32
    unsigned short* __restrict__ T,
    float* __restrict__ linD) {
  __shared__ __align__(16) unsigned short As[128 * 64];
  __shared__ __align__(16) unsigned short Bs[128 * 64];
  int m0 = blockIdx.x * 128, n0 = blockIdx.y * 128;
  int tid = threadIdx.x;
  int lane = tid & 63, wave = tid >> 6;
  int quad = lane >> 4, lrow = lane & 15;
  int wm = wave >> 1, wn = wave & 1;
  bool do_lin = (blockIdx.y == 0);

  float part[8] = {};
  floatx4 acc[4][4] = {};
  gemm_core_mixed<true>(Ut + (size_t)n0 * D_DIM, Df + (size_t)m0 * D_DIM,
                        W, do_lin, part, As, Bs, acc);

  // C/D layout: col = lane&15, row = quad*4 + reg  [m89-verified]
  #pragma unroll
  for (int mt = 0; mt < 4; ++mt)
    #pragma unroll
    for (int nt = 0; nt < 4; ++nt) {
      int row = m0 + wm * 64 + mt * 16 + quad * 4;
      int col = n0 + wn * 64 + nt * 16 + lrow;
      float bias = Ubias[col];
      #pragma unroll
      for (int rr = 0; rr < 4; ++rr)
        T[(size_t)(row + rr) * D_DIM + col] = f2bf(acc[mt][nt][rr] + bias);
    }

  if (do_lin) {                               // reduce D·W partials -> linD
    __syncthreads();                          // all As reads done
    float* red = (float*)As;                  // 128 rows x 16 = 8KB scratch
    #pragma unroll
    for (int i = 0; i < 8; ++i)
      red[(16 * i + (tid >> 4)) * 16 + (tid & 15)] = part[i];
    __syncthreads();
    if (tid < 128) {
      float s = 0.f;
      #pragma unroll
      for (int j = 0; j < 16; ++j) s += red[tid * 16 + j];
      linD[m0 + tid] = s + W[D_DIM];          // ones-column bias
    }
  }
}

// ---- GEMM2: out[b,x,y] = sum_k T[b,x,k]*bf16(H[b,y,k]) + linD + linH --------
// A = T (async); B = fp32 H (reg-staged cast).  Every block computes linH for
// its own 128 cols during staging (kept in LDS, no global round-trip).
// grid (32, 16): id%8 = b%8 -> batch's 16 blocks on one XCD (T[b]+H[b] ~ L2).
__global__ __launch_bounds__(256) void gemm2_kernel(
    const unsigned short* __restrict__ Tg,   // [32*512,1024] bf16 bits
    const float* __restrict__ Hf,            // [32*512,1024] fp32
    const float* __restrict__ Wh,            // aligned W[d+1:], len 1024
    const float* __restrict__ linD,
    float* __restrict__ out) {               // [32,512,512]
  __shared__ __align__(16) unsigned short As[128 * 64];
  __shared__ __align__(16) unsigned short Bs[128 * 64];
  __shared__ float linh_s[128];
  int b = blockIdx.x;
  int t = blockIdx.y;
  int m0 = (t >> 2) * 128, n0 = (t & 3) * 128;
  int tid = threadIdx.x;
  int lane = tid & 63, wave = tid >> 6;
  int quad = lane >> 4, lrow = lane & 15;
  int wm = wave >> 1, wn = wave & 1;

  float part[8] = {};
  floatx4 acc[4][4] = {};
  gemm_core_mixed<false>(Tg + ((size_t)b * 512 + m0) * D_DIM,
                         Hf + ((size_t)b * 512 + n0) * D_DIM,
                         Wh, true, part, As, Bs, acc);

  // reduce H·Wh partials -> linh_s (cols n0..n0+127 of this block)
  __syncthreads();                            // all Bs reads done
  float* red = (float*)Bs;
  #pragma unroll
  for (int i = 0; i < 8; ++i)
    red[(16 * i + (tid >> 4)) * 16 + (tid & 15)] = part[i];
  __syncthreads();
  if (tid < 128) {
    float s = 0.f;
    #pragma unroll
    for (int j = 0; j < 16; ++j) s += red[tid * 16 + j];
    linh_s[tid] = s;
  }
  __syncthreads();

  #pragma unroll
  for (int mt = 0; mt < 4; ++mt)
    #pragma unroll
    for (int nt = 0; nt < 4; ++nt) {
      int row = m0 + wm * 64 + mt * 16 + quad * 4;
      int col = n0 + wn * 64 + nt * 16 + lrow;
      float lh = linh_s[wn * 64 + nt * 16 + lrow];
      #pragma unroll
      for (int rr = 0; rr < 4; ++rr) {
        float v = acc[mt][nt][rr] + linD[b * 512 + row + rr] + lh;
        out[((size_t)b * 512 + row + rr) * 512 + col] = v;
      }
    }
}

extern "C" void kernel_launch(void* const* d_in, const int* in_sizes, int n_in,
                              void* d_out, int out_size, void* d_ws, size_t ws_size,
                              hipStream_t stream) {
  const float* D = (const float*)d_in[0];
  const float* H = (const float*)d_in[1];
  const float* U = (const float*)d_in[2];   // [1025,1024]
  const float* W = (const float*)d_in[3];   // [2049]
  float* out = (float*)d_out;

  char* ws = (char*)d_ws;
  unsigned short* Tbf = (unsigned short*)ws; ws += (size_t)ROWS * D_DIM * 2;   // 32 MB
  unsigned short* Ut  = (unsigned short*)ws; ws += (size_t)D_DIM * D_DIM * 2;  //  2 MB
  float* linD = (float*)ws;                  ws += (size_t)ROWS * 4;
  float* Wh   = (float*)ws;                  ws += (size_t)D_DIM * 4;          // aligned W[d+1:]

  transU_kernel<<<dim3(32, 32), 256, 0, stream>>>(U, W, Ut, Wh);
  gemm1_kernel<<<dim3(128, 8), 256, 0, stream>>>(D, Ut, U + (size_t)D_DIM * D_DIM, W, Tbf, linD);
  gemm2_kernel<<<dim3(32, 16), 256, 0, stream>>>(Tbf, H, Wh, linD, out);
}

// Round 5
// 224.079 us; speedup vs baseline: 1.0374x; 1.0097x over previous
//
#include <hip/hip_runtime.h>

// Biaffine: out[b,x,y] = Daug[b,x,:]·U·H[b,y,:] + Daug[b,x,:]·W[:d+1] + H[b,y,:]·W[d+1:]
// B=32, S=512, d=1024.  bf16 MFMA two-stage GEMM, casts fused into the GEMMs:
//   gemm1: T = bf16(D) @ Ut^T + U[d,:]   (A = fp32 D reg-staged; y==0 also linD)
//   gemm2: out[b] = T[b] @ bf16(H[b])^T + linD + linH (B = fp32 H reg-staged)
// R8: manual-sync pipelined mixed core (T14 + counted vmcnt + raw barriers).
//   R7 post-mortem: MfmaUtil 18%, VALU 17%, 1.6 TB/s — latency-bound; the
//   fp32 staging waited a full HBM round-trip per K-step and __syncthreads
//   drained vmcnt(0).  Now: fp32 tile k+1 prefetched during iter k staging and
//   kept in flight across s_barrier via explicit `s_waitcnt vmcnt(8)` (the 8
//   youngest = the prefetch; the 4 async global_load_lds retire).
//   sched_barrier(0) pins async-before-prefetch issue order; keep-alive asm
//   on the last prefetch stops DCE from changing the vmcnt count (rule #17).
//   W chunk is read from LDS (ds_read, lgkm) so the VMEM queue is exactly
//   {4 async, 8 prefetch} every iteration.
// R3 swizzle kept: LDS chunk (16B) for (row,q): c=(row>>3)*64+(row&7)*8+(q^(row&7)).

#define D_DIM 1024
#define ROWS 16384   // B*S

typedef float floatx4 __attribute__((ext_vector_type(4)));
typedef __bf16 bf16x8 __attribute__((ext_vector_type(8)));
typedef __bf16 bf16x4 __attribute__((ext_vector_type(4)));

__device__ inline unsigned short f2bf(float f) {
  unsigned int u = __builtin_bit_cast(unsigned int, f);
  u = (u + 0x7FFFu + ((u >> 16) & 1u)) >> 16;   // round-nearest-even
  return (unsigned short)u;
}

__device__ inline void async_load16(const void* g, void* l) {
  __builtin_amdgcn_global_load_lds(
      (const __attribute__((address_space(1))) void*)g,
      (__attribute__((address_space(3))) void*)l, 16, 0, 0);
}

// ---- transpose U (first 1024 rows) to bf16 Ut[n][k] = U[k][n] ---------------
// Block (0,0) additionally stages Wh = W[d+1 : 2d+1] (aligned copy; the raw
// offset is 4B-misaligned).  transU runs first on the stream.
__global__ __launch_bounds__(256) void transU_kernel(
    const float* __restrict__ U, const float* __restrict__ W,
    unsigned short* __restrict__ Ut, float* __restrict__ Wh) {
  if (blockIdx.x == 0 && blockIdx.y == 0) {
    #pragma unroll
    for (int i = 0; i < 4; ++i)
      Wh[threadIdx.x + 256 * i] = W[D_DIM + 1 + threadIdx.x + 256 * i];
  }
  __shared__ float tile[32][33];
  int n0 = blockIdx.x * 32;
  int k0 = blockIdx.y * 32;
  int t = threadIdx.x;
  int tr = t >> 5, tc = t & 31;
  #pragma unroll
  for (int i = 0; i < 32; i += 8)
    tile[tr + i][tc] = U[(size_t)(k0 + tr + i) * D_DIM + n0 + tc];
  __syncthreads();
  #pragma unroll
  for (int i = 0; i < 32; i += 8)
    Ut[(size_t)(n0 + tr + i) * D_DIM + k0 + tc] = f2bf(tile[tc][tr + i]);
}

// ---- pipelined mixed-operand MFMA core: 128x128 tile, BK=64 -----------------
// Per iter: [s_barrier] -> issue 4 async bf16 loads -> [sched_barrier] ->
// issue 8 fp32 prefetch loads (tile k+1) -> consume tile-k fp32 regs
// (lin-FMA from LDS W, cvt->bf16, swizzled ds_write) ->
// [s_waitcnt vmcnt(8) lgkmcnt(0)] (async+writes done, prefetch flying) ->
// [s_barrier] -> ds_read frags + 32 MFMA.  Prefetch latency hides under MFMA.
template <bool F32_IS_A>
__device__ inline void gemm_core_mixed(
    const unsigned short* __restrict__ Ga,  // async bf16 side, tile row 0
    const float* __restrict__ Gf,           // fp32 side, tile row 0
    bool do_lin, const float* WvS,          // lin weights in LDS (len 1024)
    float (&part)[8],
    unsigned short* As, unsigned short* Bs,
    floatx4 (&acc)[4][4]) {
  const int K = D_DIM;
  int tid = threadIdx.x;
  int l = tid & 63, wave = tid >> 6;
  int quad = l >> 4, lrow = l & 15;
  int wm = wave >> 1, wn = wave & 1;

  unsigned short* Sasync = F32_IS_A ? Bs : As;
  unsigned short* Sf32   = F32_IS_A ? As : Bs;

  int srow = 8 * wave + (l >> 3);              // +32*j per issue
  int sq = (l & 7) ^ (l >> 3);
  const unsigned short* gasync = Ga + (size_t)srow * K + sq * 8;

  int rl = lrow & 7, gofs = lrow >> 3;
  int baseA = wm * 512 + gofs * 64 + rl * 8;
  int baseB = wn * 512 + gofs * 64 + rl * 8;

  int qi = tid & 15, frow = tid >> 4;          // fp32 side: thread t = quad qi of rows 16i+frow
  const float* gf = Gf + (size_t)frow * K + qi * 4;
  int half = qi & 1, q = qi >> 1;
  int cofs[8];
  #pragma unroll
  for (int i = 0; i < 8; ++i) {
    int row = 16 * i + frow;
    cofs[i] = ((row >> 3) * 64 + (row & 7) * 8 + (q ^ (row & 7))) * 8 + half * 4;
  }

  float4 vc[8], vn[8];
  #pragma unroll
  for (int i = 0; i < 8; ++i)                  // prologue: tile 0 fp32 loads
    vc[i] = *(const float4*)(gf + (size_t)(16 * i) * K);

  for (int k0 = 0; k0 < K; k0 += 64) {
    asm volatile("" ::: "memory");
    __builtin_amdgcn_s_barrier();              // prev tile's LDS reads done (raw: no vmcnt drain)
    asm volatile("" ::: "memory");
    #pragma unroll
    for (int j = 0; j < 4; ++j)
      async_load16(gasync + (size_t)(32 * j) * K + k0, Sasync + (j * 256 + tid) * 8);
    __builtin_amdgcn_sched_barrier(0);         // async strictly older than prefetch in the queue
    int kn = (k0 + 64 < K) ? (k0 + 64) : k0;   // last iter: clamped (kept alive below)
    #pragma unroll
    for (int i = 0; i < 8; ++i)
      vn[i] = *(const float4*)(gf + (size_t)(16 * i) * K + kn);
    if (do_lin) {
      float4 wq = *(const float4*)&WvS[k0 + qi * 4];   // ds_read (lgkm, not vmcnt)
      #pragma unroll
      for (int i = 0; i < 8; ++i)
        part[i] += vc[i].x * wq.x + vc[i].y * wq.y + vc[i].z * wq.z + vc[i].w * wq.w;
    }
    #pragma unroll
    for (int i = 0; i < 8; ++i) {
      bf16x4 o = { (__bf16)vc[i].x, (__bf16)vc[i].y, (__bf16)vc[i].z, (__bf16)vc[i].w };
      *(bf16x4*)(Sf32 + cofs[i]) = o;          // ds_write_b64, conflict-free
    }
    // 12 outstanding VMEM: 4 async (old) + 8 prefetch (young). Retire async,
    // keep prefetch flying through the barrier and the MFMA phase.
    asm volatile("s_waitcnt vmcnt(8) lgkmcnt(0)" ::: "memory");
    __builtin_amdgcn_sched_barrier(0);
    __builtin_amdgcn_s_barrier();              // tile k published
    asm volatile("" ::: "memory");
    #pragma unroll
    for (int s = 0; s < 2; ++s) {
      int xq = (s * 4 + quad) ^ rl;
      bf16x8 a[4], b[4];
      #pragma unroll
      for (int mt = 0; mt < 4; ++mt)
        a[mt] = *(const bf16x8*)(As + (baseA + mt * 128 + xq) * 8);
      #pragma unroll
      for (int nt = 0; nt < 4; ++nt)
        b[nt] = *(const bf16x8*)(Bs + (baseB + nt * 128 + xq) * 8);
      #pragma unroll
      for (int mt = 0; mt < 4; ++mt)
        #pragma unroll
        for (int nt = 0; nt < 4; ++nt)
          acc[mt][nt] = __builtin_amdgcn_mfma_f32_16x16x32_bf16(
              a[mt], b[nt], acc[mt][nt], 0, 0, 0);
    }
    #pragma unroll
    for (int i = 0; i < 8; ++i) vc[i] = vn[i];
  }
  // keep the final (clamped) prefetch alive: DCE removing it would change the
  // vmcnt(8) accounting on the last iteration (rule #17).
  #pragma unroll
  for (int i = 0; i < 8; ++i)
    asm volatile("" :: "v"(vc[i].x));
}

// ---- GEMM1: T[m][n] = sum_k bf16(D[m][k]) * Ut[n][k] + Ubias[n], bf16 out ---
// A = fp32 D (reg-staged cast); B = Ut (async).  y==0 blocks compute linD.
// grid (128, 8): id%8 = mtile%8 -> 8 n-blocks sharing an A row-tile per XCD.
__global__ __launch_bounds__(256) void gemm1_kernel(
    const float* __restrict__ Df,            // [16384,1024] fp32
    const unsigned short* __restrict__ Ut,   // [1024,1024]  bf16 bits
    const float* __restrict__ Ubias,         // fp32, len 1024 (row d of U)
    const float* __restrict__ W,             // [2049] fp32
    unsigned short* __restrict__ T,
    float* __restrict__ linD) {
  __shared__ __align__(16) unsigned short As[128 * 64];
  __shared__ __align__(16) unsigned short Bs[128 * 64];
  __shared__ float WvS[1024];
  int m0 = blockIdx.x * 128, n0 = blockIdx.y * 128;
  int tid = threadIdx.x;
  int lane = tid & 63, wave = tid >> 6;
  int quad = lane >> 4, lrow = lane & 15;
  int wm = wave >> 1, wn = wave & 1;
  bool do_lin = (blockIdx.y == 0);

  ((float4*)WvS)[tid] = ((const float4*)W)[tid];   // W[0:1024] -> LDS
  __syncthreads();

  float part[8] = {};
  floatx4 acc[4][4] = {};
  gemm_core_mixed<true>(Ut + (size_t)n0 * D_DIM, Df + (size_t)m0 * D_DIM,
                        do_lin, WvS, part, As, Bs, acc);

  // C/D layout: col = lane&15, row = quad*4 + reg  [m89-verified]
  #pragma unroll
  for (int mt = 0; mt < 4; ++mt)
    #pragma unroll
    for (int nt = 0; nt < 4; ++nt) {
      int row = m0 + wm * 64 + mt * 16 + quad * 4;
      int col = n0 + wn * 64 + nt * 16 + lrow;
      float bias = Ubias[col];
      #pragma unroll
      for (int rr = 0; rr < 4; ++rr)
        T[(size_t)(row + rr) * D_DIM + col] = f2bf(acc[mt][nt][rr] + bias);
    }

  if (do_lin) {                               // reduce D·W partials -> linD
    __syncthreads();                          // all As reads done (full drain ok here)
    float* red = (float*)As;                  // 128 rows x 16 = 8KB scratch
    #pragma unroll
    for (int i = 0; i < 8; ++i)
      red[(16 * i + (tid >> 4)) * 16 + (tid & 15)] = part[i];
    __syncthreads();
    if (tid < 128) {
      float s = 0.f;
      #pragma unroll
      for (int j = 0; j < 16; ++j) s += red[tid * 16 + j];
      linD[m0 + tid] = s + W[D_DIM];          // ones-column bias
    }
  }
}

// ---- GEMM2: out[b,x,y] = sum_k T[b,x,k]*bf16(H[b,y,k]) + linD + linH --------
// A = T (async); B = fp32 H (reg-staged cast).  Every block computes linH for
// its own 128 cols during staging (kept in LDS, no global round-trip).
// grid (32, 16): id%8 = b%8 -> batch's 16 blocks on one XCD (T[b]+H[b] ~ L2).
__global__ __launch_bounds__(256) void gemm2_kernel(
    const unsigned short* __restrict__ Tg,   // [32*512,1024] bf16 bits
    const float* __restrict__ Hf,            // [32*512,1024] fp32
    const float* __restrict__ Wh,            // aligned W[d+1:], len 1024
    const float* __restrict__ linD,
    float* __restrict__ out) {               // [32,512,512]
  __shared__ __align__(16) unsigned short As[128 * 64];
  __shared__ __align__(16) unsigned short Bs[128 * 64];
  __shared__ float WvS[1024];
  __shared__ float linh_s[128];
  int b = blockIdx.x;
  int t = blockIdx.y;
  int m0 = (t >> 2) * 128, n0 = (t & 3) * 128;
  int tid = threadIdx.x;
  int lane = tid & 63, wave = tid >> 6;
  int quad = lane >> 4, lrow = lane & 15;
  int wm = wave >> 1, wn = wave & 1;

  ((float4*)WvS)[tid] = ((const float4*)Wh)[tid];  // Wh[0:1024] -> LDS
  __syncthreads();

  float part[8] = {};
  floatx4 acc[4][4] = {};
  gemm_core_mixed<false>(Tg + ((size_t)b * 512 + m0) * D_DIM,
                         Hf + ((size_t)b * 512 + n0) * D_DIM,
                         true, WvS, part, As, Bs, acc);

  // reduce H·Wh partials -> linh_s (cols n0..n0+127 of this block)
  __syncthreads();                            // all Bs reads done
  float* red = (float*)Bs;
  #pragma unroll
  for (int i = 0; i < 8; ++i)
    red[(16 * i + (tid >> 4)) * 16 + (tid & 15)] = part[i];
  __syncthreads();
  if (tid < 128) {
    float s = 0.f;
    #pragma unroll
    for (int j = 0; j < 16; ++j) s += red[tid * 16 + j];
    linh_s[tid] = s;
  }
  __syncthreads();

  #pragma unroll
  for (int mt = 0; mt < 4; ++mt)
    #pragma unroll
    for (int nt = 0; nt < 4; ++nt) {
      int row = m0 + wm * 64 + mt * 16 + quad * 4;
      int col = n0 + wn * 64 + nt * 16 + lrow;
      float lh = linh_s[wn * 64 + nt * 16 + lrow];
      #pragma unroll
      for (int rr = 0; rr < 4; ++rr) {
        float v = acc[mt][nt][rr] + linD[b * 512 + row + rr] + lh;
        out[((size_t)b * 512 + row + rr) * 512 + col] = v;
      }
    }
}

extern "C" void kernel_launch(void* const* d_in, const int* in_sizes, int n_in,
                              void* d_out, int out_size, void* d_ws, size_t ws_size,
                              hipStream_t stream) {
  const float* D = (const float*)d_in[0];
  const float* H = (const float*)d_in[1];
  const float* U = (const float*)d_in[2];   // [1025,1024]
  const float* W = (const float*)d_in[3];   // [2049]
  float* out = (float*)d_out;

  char* ws = (char*)d_ws;
  unsigned short* Tbf = (unsigned short*)ws; ws += (size_t)ROWS * D_DIM * 2;   // 32 MB
  unsigned short* Ut  = (unsigned short*)ws; ws += (size_t)D_DIM * D_DIM * 2;  //  2 MB
  float* linD = (float*)ws;                  ws += (size_t)ROWS * 4;
  float* Wh   = (float*)ws;                  ws += (size_t)D_DIM * 4;          // aligned W[d+1:]

  transU_kernel<<<dim3(32, 32), 256, 0, stream>>>(U, W, Ut, Wh);
  gemm1_kernel<<<dim3(128, 8), 256, 0, stream>>>(D, Ut, U + (size_t)D_DIM * D_DIM, W, Tbf, linD);
  gemm2_kernel<<<dim3(32, 16), 256, 0, stream>>>(Tbf, H, Wh, linD, out);
}